// Round 4
// baseline (346.304 us; speedup 1.0000x reference)
//
#include <hip/hip_runtime.h>
#include <hip/hip_bf16.h>

// CrossModalMDTA on gfx950 — round 4.
// GEMM fix: stage the ENTIRE K=192 B-stripe per block in one burst (12 b128
// loads/thread in flight -> ~50 KB/block outstanding, Little's-law BW fix),
// transpose to LDS [64n][200k] (400B row stride = 16*odd -> conflict-free
// b128 reads), ONE barrier, then barrier-free MFMA sweep over 6 k-slabs.

typedef __attribute__((ext_vector_type(8))) short short8;   // 8 x bf16
typedef __attribute__((ext_vector_type(4))) float f32x4;    // MFMA accum
typedef __attribute__((ext_vector_type(4))) float f4v;
typedef __attribute__((ext_vector_type(4))) unsigned short us4;

static __device__ __forceinline__ float b2f(unsigned short u) {
    return __uint_as_float(((unsigned)u) << 16);
}
static __device__ __forceinline__ unsigned short f2b(float f) {
    unsigned u = __float_as_uint(f);
    u += 0x7FFFu + ((u >> 16) & 1u);          // RNE
    return (unsigned short)(u >> 16);
}
static __device__ __forceinline__ unsigned short f2bh(float f) {
    union { __hip_bfloat16 h; unsigned short u; } cv;
    cv.h = __float2bfloat16(f);
    return cv.u;
}

__global__ void cvt_f2b_kernel(const float* __restrict__ src,
                               unsigned short* __restrict__ dst, int n) {
    int i = blockIdx.x * blockDim.x + threadIdx.x;
    if (i < n) dst[i] = f2b(src[i]);
}

// ---------------------------------------------------------------------------
// GEMM: C[m,n] = sum_k A[m,k]*B[k,n], K=192, N=16384. Block = 4 waves,
// tile 192m x 64n (wave w: rows 48w..48w+47, 3 mt x 4 nt).
// Whole-K staging: per thread 12 (fp32) / 6 (bf16) independent global loads
// issued before any wait -> saturates HBM; single __syncthreads().
// ---------------------------------------------------------------------------
template<typename Bty, typename Oty>
__global__ void __launch_bounds__(256) conv_gemm4(
    const unsigned short* __restrict__ A,   // bf16 [.., M, 192]
    const Bty* __restrict__ B,              // [.., 192, N] fp32 or bf16
    Oty* __restrict__ C,                    // [.., M, N] bf16(ushort) or fp32
    long aStride, long bStride, long cStride, int batch0)
{
    constexpr long N = 16384;
    constexpr int K = 192;
    const int b = batch0 + blockIdx.z;
    A += (long)b * aStride + (long)blockIdx.y * 192 * K;
    B += (long)b * bStride;
    C += (long)b * cStride + (long)blockIdx.y * 192 * N;

    const int tid  = threadIdx.x;
    const int wave = tid >> 6;
    const int lane = tid & 63;
    const int l15  = lane & 15;
    const int g    = lane >> 4;
    const long n0  = (long)blockIdx.x * 64;

    // staging identity: k-pair row, n column quad
    const int kp   = tid >> 4;          // 0..15 -> k rows {2kp, 2kp+1} per slab
    const int ncol = (tid & 15) * 4;    // 0..60

    __shared__ unsigned short Bs[64][200];   // [n][k], 400B rows (16B*25 -> clean b128)

    // ---- burst-load the whole K x 64 stripe (all loads independent) ----
    f4v ra[6], rb[6];
    us4 ua[6], ub[6];
#pragma unroll
    for (int s = 0; s < 6; ++s) {
        if constexpr (sizeof(Bty) == 4) {
            const float* bp = (const float*)B + (long)(s * 32 + 2 * kp) * N + n0 + ncol;
            ra[s] = *reinterpret_cast<const f4v*>(bp);
            rb[s] = *reinterpret_cast<const f4v*>(bp + N);
        } else {
            const unsigned short* bp =
                (const unsigned short*)B + (long)(s * 32 + 2 * kp) * N + n0 + ncol;
            ua[s] = *reinterpret_cast<const us4*>(bp);
            ub[s] = *reinterpret_cast<const us4*>(bp + N);
        }
    }
    // ---- transpose into LDS (bf16 pairs packed as u32) ----
#pragma unroll
    for (int s = 0; s < 6; ++s) {
#pragma unroll
        for (int i = 0; i < 4; ++i) {
            unsigned u;
            if constexpr (sizeof(Bty) == 4)
                u = (unsigned)f2bh(ra[s][i]) | ((unsigned)f2bh(rb[s][i]) << 16);
            else
                u = (unsigned)ua[s][i] | ((unsigned)ub[s][i] << 16);
            *reinterpret_cast<unsigned*>(&Bs[ncol + i][s * 32 + 2 * kp]) = u;
        }
    }
    __syncthreads();   // the only barrier

    f32x4 acc[3][4];
#pragma unroll
    for (int i = 0; i < 3; ++i)
#pragma unroll
        for (int j = 0; j < 4; ++j) acc[i][j] = {0.f, 0.f, 0.f, 0.f};

#pragma unroll
    for (int s = 0; s < 6; ++s) {
        short8 af[3];
#pragma unroll
        for (int mt = 0; mt < 3; ++mt)
            af[mt] = *reinterpret_cast<const short8*>(
                A + (long)(wave * 48 + mt * 16 + l15) * K + s * 32 + g * 8);
        short8 bf[4];
#pragma unroll
        for (int nt = 0; nt < 4; ++nt)
            bf[nt] = *reinterpret_cast<const short8*>(&Bs[nt * 16 + l15][s * 32 + g * 8]);
#pragma unroll
        for (int nt = 0; nt < 4; ++nt)
#pragma unroll
            for (int mt = 0; mt < 3; ++mt)
                acc[mt][nt] = __builtin_amdgcn_mfma_f32_16x16x32_bf16(
                    af[mt], bf[nt], acc[mt][nt], 0, 0, 0);
    }

    // epilogue: D row = (lane>>4)*4 + r, col = lane&15
#pragma unroll
    for (int mt = 0; mt < 3; ++mt) {
#pragma unroll
        for (int nt = 0; nt < 4; ++nt) {
            const int row = wave * 48 + mt * 16 + g * 4;
            const long col = n0 + nt * 16 + l15;
#pragma unroll
            for (int r = 0; r < 4; ++r) {
                const float v = acc[mt][nt][r];
                if constexpr (sizeof(Oty) == 4)
                    C[(long)(row + r) * N + col] = v;
                else
                    C[(long)(row + r) * N + col] = f2b(v);
            }
        }
    }
}

// ---------------------------------------------------------------------------
// depthwise 3x3 (SAME, zero pad), bf16 in/out, fp32 accum.
// Emits per-(b,channel) sum-of-squares partials (channels < 192 only).
// ---------------------------------------------------------------------------
__global__ void __launch_bounds__(256) dw3x3(
    const unsigned short* __restrict__ src,
    unsigned short* __restrict__ dst,
    const float* __restrict__ wdw,          // [C][9] fp32
    float* __restrict__ normPart,           // [B][192][32] fp32
    int C, long srcStride, long dstStride, int batch0)
{
    const int b  = batch0 + blockIdx.z;
    const int t  = blockIdx.x * 256 + threadIdx.x;
    const int w0 = (t & 15) * 8;
    const int hh = (t >> 4) & 127;
    const int c  = t >> 11;                  // 2048 threads per channel
    if (c >= C) return;

    const unsigned short* s = src + (long)b * srcStride + ((long)c << 14);
    float wt[9];
#pragma unroll
    for (int i = 0; i < 9; ++i) wt[i] = wdw[c * 9 + i];

    float acc[8] = {0, 0, 0, 0, 0, 0, 0, 0};
#pragma unroll
    for (int dy = 0; dy < 3; ++dy) {
        const int hy = hh + dy - 1;
        if (hy < 0 || hy > 127) continue;
        const unsigned short* row = s + hy * 128 + w0;
        float r[10];
        const short8 v = *reinterpret_cast<const short8*>(row);
#pragma unroll
        for (int i = 0; i < 8; ++i) r[i + 1] = b2f((unsigned short)v[i]);
        r[0] = (w0 > 0)   ? b2f(row[-1]) : 0.f;
        r[9] = (w0 < 120) ? b2f(row[8])  : 0.f;
#pragma unroll
        for (int j = 0; j < 8; ++j)
            acc[j] += wt[dy*3+0]*r[j] + wt[dy*3+1]*r[j+1] + wt[dy*3+2]*r[j+2];
    }

    short8 o;
#pragma unroll
    for (int j = 0; j < 8; ++j) o[j] = (short)f2b(acc[j]);
    *reinterpret_cast<short8*>(dst + (long)b * dstStride + ((long)c << 14)
                               + hh * 128 + w0) = o;

    if (c < 192) {
        float ssq = 0.f;
#pragma unroll
        for (int j = 0; j < 8; ++j) ssq += acc[j] * acc[j];
#pragma unroll
        for (int ofs = 1; ofs < 64; ofs <<= 1) ssq += __shfl_xor(ssq, ofs);
        if ((threadIdx.x & 63) == 0)
            normPart[((long)b * 192 + c) * 32 + ((t & 2047) >> 6)] = ssq;
    }
}

// ---------------------------------------------------------------------------
// Gram: G[d,e] = sum_n q[d,n]*k[e,n] per (b,h), N chunked into 16 x 1024.
// ---------------------------------------------------------------------------
__global__ void __launch_bounds__(256) gram_kernel(
    const unsigned short* __restrict__ q,    // [B,192,N] bf16
    const unsigned short* __restrict__ kv,   // [B,384,N] bf16 (k = first 192)
    float* __restrict__ Gpart)               // [B,4,16,2304]
{
    constexpr long N = 16384;
    const int chunk = blockIdx.x, h = blockIdx.y, b = blockIdx.z;
    const int tid = threadIdx.x;
    const int wave = tid >> 6, lane = tid & 63;
    const int l15 = lane & 15, g = lane >> 4;
    const unsigned short* qp = q  + ((long)b * 192 + h * 48) * N;
    const unsigned short* kp = kv + ((long)b * 384 + h * 48) * N;
    const int nbase = chunk * 1024 + wave * 256;

    f32x4 acc[3][3];
#pragma unroll
    for (int i = 0; i < 3; ++i)
#pragma unroll
        for (int j = 0; j < 3; ++j) acc[i][j] = {0.f, 0.f, 0.f, 0.f};

    for (int s = 0; s < 8; ++s) {
        const long n0 = nbase + s * 32 + g * 8;
        short8 af[3], bf[3];
#pragma unroll
        for (int mt = 0; mt < 3; ++mt)
            af[mt] = *reinterpret_cast<const short8*>(qp + (long)(mt*16 + l15) * N + n0);
#pragma unroll
        for (int nt = 0; nt < 3; ++nt)
            bf[nt] = *reinterpret_cast<const short8*>(kp + (long)(nt*16 + l15) * N + n0);
#pragma unroll
        for (int mt = 0; mt < 3; ++mt)
#pragma unroll
            for (int nt = 0; nt < 3; ++nt)
                acc[mt][nt] = __builtin_amdgcn_mfma_f32_16x16x32_bf16(
                    af[mt], bf[nt], acc[mt][nt], 0, 0, 0);
    }

    __shared__ float Gt[4][2304];
#pragma unroll
    for (int mt = 0; mt < 3; ++mt)
#pragma unroll
        for (int nt = 0; nt < 3; ++nt)
#pragma unroll
            for (int r = 0; r < 4; ++r)
                Gt[wave][(mt*16 + g*4 + r) * 48 + nt*16 + l15] = acc[mt][nt][r];
    __syncthreads();

    float* gout = Gpart + (((long)(b * 4 + h)) * 16 + chunk) * 2304;
    for (int i = tid; i < 2304; i += 256)
        gout[i] = Gt[0][i] + Gt[1][i] + Gt[2][i] + Gt[3][i];
}

// ---------------------------------------------------------------------------
// Per (b,h): reduce partials, softmax(G/(nq*nk)*T), fold w_out:
// M[c, 48h+e] = sum_d w_out[c, 48h+d] * attn[d,e]
// ---------------------------------------------------------------------------
__global__ void __launch_bounds__(256) attn_m_kernel(
    const float* __restrict__ Gpart,        // [B,4,16,2304]
    const float* __restrict__ nqPart,       // [B,192,32]
    const float* __restrict__ nkPart,       // [B,192,32]
    const float* __restrict__ w_out,        // [192,192] fp32
    const float* __restrict__ temperature,  // [4]
    unsigned short* __restrict__ Mmat)      // [B,192,192] bf16
{
    const int blk = blockIdx.x;
    const int b = blk >> 2, h = blk & 3;
    const int tid = threadIdx.x;
    __shared__ float G[2304];
    __shared__ float At[2304];
    __shared__ float nqv[48], nkv[48];

    const long base = ((long)(b * 4 + h)) * 16;
    for (int i = tid; i < 2304; i += 256) {
        float s = 0.f;
        for (int c = 0; c < 16; ++c) s += Gpart[(base + c) * 2304 + i];
        G[i] = s;
    }
    if (tid < 96) {
        const int isK = tid >= 48;
        const int d = tid - 48 * isK;
        const float* p = (isK ? nkPart : nqPart) + ((long)b * 192 + h * 48 + d) * 32;
        float s = 0.f;
        for (int i = 0; i < 32; ++i) s += p[i];
        const float nrm = fmaxf(sqrtf(s), 1e-12f);
        if (isK) nkv[d] = nrm; else nqv[d] = nrm;
    }
    __syncthreads();

    const float T = temperature[h];
    if (tid < 48) {
        const int d = tid;
        const float scale = T / nqv[d];
        float m = -1e30f;
        for (int e = 0; e < 48; ++e) {
            const float sv = G[d * 48 + e] * scale / nkv[e];
            At[d * 48 + e] = sv;
            m = fmaxf(m, sv);
        }
        float sum = 0.f;
        for (int e = 0; e < 48; ++e) {
            const float ex = expf(At[d * 48 + e] - m);
            At[d * 48 + e] = ex;
            sum += ex;
        }
        const float inv = 1.f / sum;
        for (int e = 0; e < 48; ++e) At[d * 48 + e] *= inv;
    }
    __syncthreads();

    for (int i = tid; i < 192 * 48; i += 256) {
        const int c = i / 48, e = i - (i / 48) * 48;
        const float* wrow = w_out + (long)c * 192 + h * 48;
        float s = 0.f;
        for (int d = 0; d < 48; ++d) s += wrow[d] * At[d * 48 + e];
        Mmat[((long)b * 192 + c) * 192 + h * 48 + e] = f2b(s);
    }
}

// ---------------------------------------------------------------------------
extern "C" void kernel_launch(void* const* d_in, const int* in_sizes, int n_in,
                              void* d_out, int out_size, void* d_ws, size_t ws_size,
                              hipStream_t stream)
{
    const float* f_opt  = (const float*)d_in[0];
    const float* f_sar  = (const float*)d_in[1];
    const float* w_q    = (const float*)d_in[2];
    const float* w_qdw  = (const float*)d_in[3];
    const float* w_kv   = (const float*)d_in[4];
    const float* w_kvdw = (const float*)d_in[5];
    const float* w_out  = (const float*)d_in[6];
    const float* temper = (const float*)d_in[7];
    float* out = (float*)d_out;

    const long N = 16384;
    char* ws = (char*)d_ws;
    size_t off = 0;
    auto alloc = [&](size_t bytes) -> void* {
        void* p = ws + off;
        off = (off + bytes + 255) & ~(size_t)255;
        return p;
    };

    unsigned short* wq_b  = (unsigned short*)alloc((size_t)192 * 192 * 2);
    unsigned short* wkv_b = (unsigned short*)alloc((size_t)384 * 192 * 2);
    unsigned short* Mmat  = (unsigned short*)alloc((size_t)8 * 192 * 192 * 2);
    float* Gpart  = (float*)alloc((size_t)8 * 4 * 16 * 2304 * 4);
    float* nqPart = (float*)alloc((size_t)8 * 192 * 32 * 4);
    float* nkPart = (float*)alloc((size_t)8 * 192 * 32 * 4);
    unsigned short* qbuf  = (unsigned short*)alloc((size_t)8 * 192 * N * 2);
    unsigned short* kvbuf = (unsigned short*)alloc((size_t)8 * 384 * N * 2);

    const size_t fullNeed = off + ((size_t)8 * 192 * N * 2 + 256)
                                + ((size_t)8 * 384 * N * 2 + 256);
    const bool full = (ws_size >= fullNeed);

    unsigned short *q0, *kv0;
    long q0S, kv0S; int nz;
    if (full) {
        q0  = (unsigned short*)alloc((size_t)8 * 192 * N * 2);
        kv0 = (unsigned short*)alloc((size_t)8 * 384 * N * 2);
        q0S = 192 * N; kv0S = 384 * N; nz = 8;
    } else {
        q0  = (unsigned short*)alloc((size_t)192 * N * 2);
        kv0 = (unsigned short*)alloc((size_t)384 * N * 2);
        q0S = 0; kv0S = 0; nz = 1;
    }

    cvt_f2b_kernel<<<dim3((192*192 + 255) / 256), 256, 0, stream>>>(w_q,  wq_b,  192*192);
    cvt_f2b_kernel<<<dim3((384*192 + 255) / 256), 256, 0, stream>>>(w_kv, wkv_b, 384*192);

    const int iters = full ? 1 : 8;
    for (int it = 0; it < iters; ++it) {
        const int b0 = full ? 0 : it;
        conv_gemm4<float, unsigned short><<<dim3(256, 1, nz), 256, 0, stream>>>(
            wq_b, f_opt, q0, 0, 192 * N, q0S, b0);
        dw3x3<<<dim3(1536, 1, nz), 256, 0, stream>>>(
            q0, qbuf, w_qdw, nqPart, 192, q0S, 192 * N, b0);
        conv_gemm4<float, unsigned short><<<dim3(256, 2, nz), 256, 0, stream>>>(
            wkv_b, f_sar, kv0, 0, 192 * N, kv0S, b0);
        dw3x3<<<dim3(3072, 1, nz), 256, 0, stream>>>(
            kv0, kvbuf, w_kvdw, nkPart, 384, kv0S, 384 * N, b0);
    }

    gram_kernel<<<dim3(16, 4, 8), 256, 0, stream>>>(qbuf, kvbuf, Gpart);
    attn_m_kernel<<<dim3(32), 256, 0, stream>>>(Gpart, nqPart, nkPart, w_out, temper, Mmat);

    // out = M_b @ v  (v = channels 192..383 of kv)
    conv_gemm4<unsigned short, float><<<dim3(256, 1, 8), 256, 0, stream>>>(
        Mmat, kvbuf + 192 * N, out, (long)192 * 192, 384 * N, 192 * N, 0);
}

// Round 5
// 305.125 us; speedup vs baseline: 1.1350x; 1.1350x over previous
//
#include <hip/hip_runtime.h>
#include <hip/hip_bf16.h>

// CrossModalMDTA on gfx950 — round 5.
// GEMM: BN=128 (2x wider column stripes -> 2x fewer 4KB-page touches per byte,
// 512B/row DRAM bursts), k-packed ds_write_b128 staging, whole-K LDS, 1 barrier.
// q-conv and kv-conv merged into ONE dispatch (blockIdx.y group select).

typedef __attribute__((ext_vector_type(8))) short short8;   // 8 x bf16
typedef __attribute__((ext_vector_type(4))) float f32x4;    // MFMA accum

static __device__ __forceinline__ float b2f(unsigned short u) {
    return __uint_as_float(((unsigned)u) << 16);
}
static __device__ __forceinline__ unsigned short f2b(float f) {
    unsigned u = __float_as_uint(f);
    u += 0x7FFFu + ((u >> 16) & 1u);          // RNE
    return (unsigned short)(u >> 16);
}
static __device__ __forceinline__ unsigned short f2bh(float f) {
    union { __hip_bfloat16 h; unsigned short u; } cv;
    cv.h = __float2bfloat16(f);
    return cv.u;
}

__global__ void cvt_f2b_kernel(const float* __restrict__ src,
                               unsigned short* __restrict__ dst, int n) {
    int i = blockIdx.x * blockDim.x + threadIdx.x;
    if (i < n) dst[i] = f2b(src[i]);
}

// ---------------------------------------------------------------------------
// GEMM body: C[m,n] = sum_k A[m,k]*B[k,n], K=192, N=16384, M=192 per group.
// Block = 4 waves, tile 192m x 128n (wave w: rows 48w..48w+47, 3 mt x 8 nt).
// Staging: thread owns (n-col, k-chunk-of-8): 8 coalesced dword loads
// (256B/instr), pack to bf16 pairs, one ds_write_b128. Bs[n][k] rows 400B.
// ---------------------------------------------------------------------------
template<typename Bty, typename Oty>
static __device__ __forceinline__ void gemm_body(
    const unsigned short* __restrict__ A,   // bf16 [192 x 192]
    const Bty* __restrict__ B,              // [192 x N] fp32 or bf16
    Oty* __restrict__ C)                    // [192 x N] bf16(ushort) or fp32
{
    constexpr long N = 16384;
    constexpr int K = 192;
    const int tid  = threadIdx.x;
    const int wave = tid >> 6;
    const int lane = tid & 63;
    const int l15  = lane & 15;
    const int g    = lane >> 4;
    const long n0  = (long)blockIdx.x * 128;

    __shared__ unsigned short Bs[128][200];   // 51.2 KB, rows 400B (16B-aligned)

    // staging identity: n-column + k-chunk
    const int nc = tid & 127;       // 0..127
    const int kb = tid >> 7;        // 0..1

#pragma unroll 3
    for (int i = 0; i < 12; ++i) {
        const int kc = kb + 2 * i;              // 0..23 k-chunks of 8
        const Bty* bp = B + (long)(kc * 8) * N + n0 + nc;
        unsigned w[4];
        if constexpr (sizeof(Bty) == 4) {
            float v[8];
#pragma unroll
            for (int j = 0; j < 8; ++j) v[j] = (float)bp[j * N];
#pragma unroll
            for (int t = 0; t < 4; ++t)
                w[t] = (unsigned)f2bh(v[2*t]) | ((unsigned)f2bh(v[2*t+1]) << 16);
        } else {
            unsigned short v[8];
#pragma unroll
            for (int j = 0; j < 8; ++j) v[j] = bp[j * N];
#pragma unroll
            for (int t = 0; t < 4; ++t)
                w[t] = (unsigned)v[2*t] | ((unsigned)v[2*t+1] << 16);
        }
        uint4 pk = {w[0], w[1], w[2], w[3]};
        *reinterpret_cast<uint4*>(&Bs[nc][kc * 8]) = pk;
    }
    __syncthreads();   // the only barrier

    f32x4 acc[3][8];
#pragma unroll
    for (int i = 0; i < 3; ++i)
#pragma unroll
        for (int j = 0; j < 8; ++j) acc[i][j] = {0.f, 0.f, 0.f, 0.f};

#pragma unroll
    for (int s = 0; s < 6; ++s) {
        short8 af[3];
#pragma unroll
        for (int mt = 0; mt < 3; ++mt)
            af[mt] = *reinterpret_cast<const short8*>(
                A + (long)(wave * 48 + mt * 16 + l15) * K + s * 32 + g * 8);
        short8 bf[8];
#pragma unroll
        for (int nt = 0; nt < 8; ++nt)
            bf[nt] = *reinterpret_cast<const short8*>(&Bs[nt * 16 + l15][s * 32 + g * 8]);
#pragma unroll
        for (int nt = 0; nt < 8; ++nt)
#pragma unroll
            for (int mt = 0; mt < 3; ++mt)
                acc[mt][nt] = __builtin_amdgcn_mfma_f32_16x16x32_bf16(
                    af[mt], bf[nt], acc[mt][nt], 0, 0, 0);
    }

    // epilogue: D row = (lane>>4)*4 + r, col = lane&15
#pragma unroll
    for (int mt = 0; mt < 3; ++mt) {
#pragma unroll
        for (int nt = 0; nt < 8; ++nt) {
            const int row = wave * 48 + mt * 16 + g * 4;
            const long col = n0 + nt * 16 + l15;
#pragma unroll
            for (int r = 0; r < 4; ++r) {
                const float v = acc[mt][nt][r];
                if constexpr (sizeof(Oty) == 4)
                    C[(long)(row + r) * N + col] = v;
                else
                    C[(long)(row + r) * N + col] = f2b(v);
            }
        }
    }
}

// fused q + kv projection: y==0 -> q0 = Wq*f_opt ; y==1,2 -> kv0 rows
__global__ void __launch_bounds__(256) proj_gemm(
    const unsigned short* __restrict__ wq_b,   // [192x192] bf16
    const unsigned short* __restrict__ wkv_b,  // [384x192] bf16
    const float* __restrict__ f_opt,
    const float* __restrict__ f_sar,
    unsigned short* __restrict__ q0,
    unsigned short* __restrict__ kv0,
    long q0S, long kv0S, int batch0)
{
    constexpr long N = 16384;
    const int b = batch0 + blockIdx.z;
    const int y = blockIdx.y;
    if (y == 0) {
        gemm_body<float, unsigned short>(
            wq_b, f_opt + (long)b * 192 * N, q0 + (long)b * q0S);
    } else {
        gemm_body<float, unsigned short>(
            wkv_b + (long)(y - 1) * 192 * 192,
            f_sar + (long)b * 192 * N,
            kv0 + (long)b * kv0S + (long)(y - 1) * 192 * N);
    }
}

// final: out = M_b @ v
__global__ void __launch_bounds__(256) final_gemm(
    const unsigned short* __restrict__ Mmat,   // [B,192,192] bf16
    const unsigned short* __restrict__ v,      // [B*384,N] bf16 (offset to v rows)
    float* __restrict__ out, long vStride)
{
    constexpr long N = 16384;
    const int b = blockIdx.z;
    gemm_body<unsigned short, float>(
        Mmat + (long)b * 192 * 192, v + (long)b * vStride, out + (long)b * 192 * N);
}

// ---------------------------------------------------------------------------
// depthwise 3x3 (SAME, zero pad), bf16 in/out, fp32 accum.
// Emits per-(b,channel) sum-of-squares partials (channels < 192 only).
// ---------------------------------------------------------------------------
__global__ void __launch_bounds__(256) dw3x3(
    const unsigned short* __restrict__ src,
    unsigned short* __restrict__ dst,
    const float* __restrict__ wdw,          // [C][9] fp32
    float* __restrict__ normPart,           // [B][192][32] fp32
    int C, long srcStride, long dstStride, int batch0)
{
    const int b  = batch0 + blockIdx.z;
    const int t  = blockIdx.x * 256 + threadIdx.x;
    const int w0 = (t & 15) * 8;
    const int hh = (t >> 4) & 127;
    const int c  = t >> 11;                  // 2048 threads per channel
    if (c >= C) return;

    const unsigned short* s = src + (long)b * srcStride + ((long)c << 14);
    float wt[9];
#pragma unroll
    for (int i = 0; i < 9; ++i) wt[i] = wdw[c * 9 + i];

    float acc[8] = {0, 0, 0, 0, 0, 0, 0, 0};
#pragma unroll
    for (int dy = 0; dy < 3; ++dy) {
        const int hy = hh + dy - 1;
        if (hy < 0 || hy > 127) continue;
        const unsigned short* row = s + hy * 128 + w0;
        float r[10];
        const short8 v = *reinterpret_cast<const short8*>(row);
#pragma unroll
        for (int i = 0; i < 8; ++i) r[i + 1] = b2f((unsigned short)v[i]);
        r[0] = (w0 > 0)   ? b2f(row[-1]) : 0.f;
        r[9] = (w0 < 120) ? b2f(row[8])  : 0.f;
#pragma unroll
        for (int j = 0; j < 8; ++j)
            acc[j] += wt[dy*3+0]*r[j] + wt[dy*3+1]*r[j+1] + wt[dy*3+2]*r[j+2];
    }

    short8 o;
#pragma unroll
    for (int j = 0; j < 8; ++j) o[j] = (short)f2b(acc[j]);
    *reinterpret_cast<short8*>(dst + (long)b * dstStride + ((long)c << 14)
                               + hh * 128 + w0) = o;

    if (c < 192) {
        float ssq = 0.f;
#pragma unroll
        for (int j = 0; j < 8; ++j) ssq += acc[j] * acc[j];
#pragma unroll
        for (int ofs = 1; ofs < 64; ofs <<= 1) ssq += __shfl_xor(ssq, ofs);
        if ((threadIdx.x & 63) == 0)
            normPart[((long)b * 192 + c) * 32 + ((t & 2047) >> 6)] = ssq;
    }
}

// ---------------------------------------------------------------------------
// Gram: G[d,e] = sum_n q[d,n]*k[e,n] per (b,h), N chunked into 16 x 1024.
// ---------------------------------------------------------------------------
__global__ void __launch_bounds__(256) gram_kernel(
    const unsigned short* __restrict__ q,    // [B,192,N] bf16
    const unsigned short* __restrict__ kv,   // [B,384,N] bf16 (k = first 192)
    float* __restrict__ Gpart)               // [B,4,16,2304]
{
    constexpr long N = 16384;
    const int chunk = blockIdx.x, h = blockIdx.y, b = blockIdx.z;
    const int tid = threadIdx.x;
    const int wave = tid >> 6, lane = tid & 63;
    const int l15 = lane & 15, g = lane >> 4;
    const unsigned short* qp = q  + ((long)b * 192 + h * 48) * N;
    const unsigned short* kp = kv + ((long)b * 384 + h * 48) * N;
    const int nbase = chunk * 1024 + wave * 256;

    f32x4 acc[3][3];
#pragma unroll
    for (int i = 0; i < 3; ++i)
#pragma unroll
        for (int j = 0; j < 3; ++j) acc[i][j] = {0.f, 0.f, 0.f, 0.f};

    for (int s = 0; s < 8; ++s) {
        const long n0 = nbase + s * 32 + g * 8;
        short8 af[3], bf[3];
#pragma unroll
        for (int mt = 0; mt < 3; ++mt)
            af[mt] = *reinterpret_cast<const short8*>(qp + (long)(mt*16 + l15) * N + n0);
#pragma unroll
        for (int nt = 0; nt < 3; ++nt)
            bf[nt] = *reinterpret_cast<const short8*>(kp + (long)(nt*16 + l15) * N + n0);
#pragma unroll
        for (int mt = 0; mt < 3; ++mt)
#pragma unroll
            for (int nt = 0; nt < 3; ++nt)
                acc[mt][nt] = __builtin_amdgcn_mfma_f32_16x16x32_bf16(
                    af[mt], bf[nt], acc[mt][nt], 0, 0, 0);
    }

    __shared__ float Gt[4][2304];
#pragma unroll
    for (int mt = 0; mt < 3; ++mt)
#pragma unroll
        for (int nt = 0; nt < 3; ++nt)
#pragma unroll
            for (int r = 0; r < 4; ++r)
                Gt[wave][(mt*16 + g*4 + r) * 48 + nt*16 + l15] = acc[mt][nt][r];
    __syncthreads();

    float* gout = Gpart + (((long)(b * 4 + h)) * 16 + chunk) * 2304;
    for (int i = tid; i < 2304; i += 256)
        gout[i] = Gt[0][i] + Gt[1][i] + Gt[2][i] + Gt[3][i];
}

// ---------------------------------------------------------------------------
// Per (b,h): reduce partials, softmax(G/(nq*nk)*T), fold w_out:
// M[c, 48h+e] = sum_d w_out[c, 48h+d] * attn[d,e]
// ---------------------------------------------------------------------------
__global__ void __launch_bounds__(256) attn_m_kernel(
    const float* __restrict__ Gpart,        // [B,4,16,2304]
    const float* __restrict__ nqPart,       // [B,192,32]
    const float* __restrict__ nkPart,       // [B,192,32]
    const float* __restrict__ w_out,        // [192,192] fp32
    const float* __restrict__ temperature,  // [4]
    unsigned short* __restrict__ Mmat)      // [B,192,192] bf16
{
    const int blk = blockIdx.x;
    const int b = blk >> 2, h = blk & 3;
    const int tid = threadIdx.x;
    __shared__ float G[2304];
    __shared__ float At[2304];
    __shared__ float nqv[48], nkv[48];

    const long base = ((long)(b * 4 + h)) * 16;
    for (int i = tid; i < 2304; i += 256) {
        float s = 0.f;
        for (int c = 0; c < 16; ++c) s += Gpart[(base + c) * 2304 + i];
        G[i] = s;
    }
    if (tid < 96) {
        const int isK = tid >= 48;
        const int d = tid - 48 * isK;
        const float* p = (isK ? nkPart : nqPart) + ((long)b * 192 + h * 48 + d) * 32;
        float s = 0.f;
        for (int i = 0; i < 32; ++i) s += p[i];
        const float nrm = fmaxf(sqrtf(s), 1e-12f);
        if (isK) nkv[d] = nrm; else nqv[d] = nrm;
    }
    __syncthreads();

    const float T = temperature[h];
    if (tid < 48) {
        const int d = tid;
        const float scale = T / nqv[d];
        float m = -1e30f;
        for (int e = 0; e < 48; ++e) {
            const float sv = G[d * 48 + e] * scale / nkv[e];
            At[d * 48 + e] = sv;
            m = fmaxf(m, sv);
        }
        float sum = 0.f;
        for (int e = 0; e < 48; ++e) {
            const float ex = expf(At[d * 48 + e] - m);
            At[d * 48 + e] = ex;
            sum += ex;
        }
        const float inv = 1.f / sum;
        for (int e = 0; e < 48; ++e) At[d * 48 + e] *= inv;
    }
    __syncthreads();

    for (int i = tid; i < 192 * 48; i += 256) {
        const int c = i / 48, e = i - (i / 48) * 48;
        const float* wrow = w_out + (long)c * 192 + h * 48;
        float s = 0.f;
        for (int d = 0; d < 48; ++d) s += wrow[d] * At[d * 48 + e];
        Mmat[((long)b * 192 + c) * 192 + h * 48 + e] = f2b(s);
    }
}

// ---------------------------------------------------------------------------
extern "C" void kernel_launch(void* const* d_in, const int* in_sizes, int n_in,
                              void* d_out, int out_size, void* d_ws, size_t ws_size,
                              hipStream_t stream)
{
    const float* f_opt  = (const float*)d_in[0];
    const float* f_sar  = (const float*)d_in[1];
    const float* w_q    = (const float*)d_in[2];
    const float* w_qdw  = (const float*)d_in[3];
    const float* w_kv   = (const float*)d_in[4];
    const float* w_kvdw = (const float*)d_in[5];
    const float* w_out  = (const float*)d_in[6];
    const float* temper = (const float*)d_in[7];
    float* out = (float*)d_out;

    const long N = 16384;
    char* ws = (char*)d_ws;
    size_t off = 0;
    auto alloc = [&](size_t bytes) -> void* {
        void* p = ws + off;
        off = (off + bytes + 255) & ~(size_t)255;
        return p;
    };

    unsigned short* wq_b  = (unsigned short*)alloc((size_t)192 * 192 * 2);
    unsigned short* wkv_b = (unsigned short*)alloc((size_t)384 * 192 * 2);
    unsigned short* Mmat  = (unsigned short*)alloc((size_t)8 * 192 * 192 * 2);
    float* Gpart  = (float*)alloc((size_t)8 * 4 * 16 * 2304 * 4);
    float* nqPart = (float*)alloc((size_t)8 * 192 * 32 * 4);
    float* nkPart = (float*)alloc((size_t)8 * 192 * 32 * 4);
    unsigned short* qbuf  = (unsigned short*)alloc((size_t)8 * 192 * N * 2);
    unsigned short* kvbuf = (unsigned short*)alloc((size_t)8 * 384 * N * 2);

    const size_t fullNeed = off + ((size_t)8 * 192 * N * 2 + 256)
                                + ((size_t)8 * 384 * N * 2 + 256);
    const bool full = (ws_size >= fullNeed);

    unsigned short *q0, *kv0;
    long q0S, kv0S; int nz;
    if (full) {
        q0  = (unsigned short*)alloc((size_t)8 * 192 * N * 2);
        kv0 = (unsigned short*)alloc((size_t)8 * 384 * N * 2);
        q0S = 192 * N; kv0S = 384 * N; nz = 8;
    } else {
        q0  = (unsigned short*)alloc((size_t)192 * N * 2);
        kv0 = (unsigned short*)alloc((size_t)384 * N * 2);
        q0S = 0; kv0S = 0; nz = 1;
    }

    cvt_f2b_kernel<<<dim3((192*192 + 255) / 256), 256, 0, stream>>>(w_q,  wq_b,  192*192);
    cvt_f2b_kernel<<<dim3((384*192 + 255) / 256), 256, 0, stream>>>(w_kv, wkv_b, 384*192);

    const int iters = full ? 1 : 8;
    for (int it = 0; it < iters; ++it) {
        const int b0 = full ? 0 : it;
        proj_gemm<<<dim3(128, 3, nz), 256, 0, stream>>>(
            wq_b, wkv_b, f_opt, f_sar, q0, kv0, q0S, kv0S, b0);
        dw3x3<<<dim3(1536, 1, nz), 256, 0, stream>>>(
            q0, qbuf, w_qdw, nqPart, 192, q0S, 192 * N, b0);
        dw3x3<<<dim3(3072, 1, nz), 256, 0, stream>>>(
            kv0, kvbuf, w_kvdw, nkPart, 384, kv0S, 384 * N, b0);
    }

    gram_kernel<<<dim3(16, 4, 8), 256, 0, stream>>>(qbuf, kvbuf, Gpart);
    attn_m_kernel<<<dim3(32), 256, 0, stream>>>(Gpart, nqPart, nkPart, w_out, temper, Mmat);

    // out = M_b @ v  (v = channels 192..383 of kv)
    final_gemm<<<dim3(128, 1, 8), 256, 0, stream>>>(
        Mmat, kvbuf + 192 * N, out, 384 * N);
}